// Round 1
// baseline (95.896 us; speedup 1.0000x reference)
//
#include <hip/hip_runtime.h>

// loss = mean over all elements of (sigmoid(x) - t)^2 * ((1-t) + (x<=0 ? 1 : 0))
// Derivation: distance_transform(m) == 1 - m for binary m (center tap of the
// 3x3 ones conv guarantees iteration 1 returns `inverted`; iteration 2 breaks).
// dt^2 = (1-t)^2 = 1-t since t in {0,1}; preds = (sigmoid(x)>0.5) = (x>0).

__device__ __forceinline__ float loss_term(float x, float t) {
    float p = 1.0f / (1.0f + __expf(-x));
    float d = p - t;
    float w = (1.0f - t) + (x > 0.0f ? 0.0f : 1.0f);
    return d * d * w;
}

// Block-level reduce of one float per thread; returns total to thread 0.
__device__ __forceinline__ float block_reduce(float v) {
    // wave64 butterfly
    #pragma unroll
    for (int off = 32; off > 0; off >>= 1)
        v += __shfl_down(v, off, 64);
    __shared__ float smem[16];               // up to 1024 threads = 16 waves
    const int lane = threadIdx.x & 63;
    const int wave = threadIdx.x >> 6;
    if (lane == 0) smem[wave] = v;
    __syncthreads();
    float s = 0.0f;
    if (threadIdx.x == 0) {
        const int nwaves = (blockDim.x + 63) >> 6;
        for (int w = 0; w < nwaves; ++w) s += smem[w];
    }
    return s;
}

__global__ void hausdorff_partial(const float* __restrict__ logits,
                                  const float* __restrict__ targets,
                                  float* __restrict__ partial,
                                  int n) {
    const int tid    = blockIdx.x * blockDim.x + threadIdx.x;
    const int stride = gridDim.x * blockDim.x;
    const int n4     = n >> 2;

    const float4* __restrict__ x4 = (const float4*)logits;
    const float4* __restrict__ t4 = (const float4*)targets;

    float acc = 0.0f;
    for (int i = tid; i < n4; i += stride) {
        float4 x = x4[i];
        float4 t = t4[i];
        acc += loss_term(x.x, t.x);
        acc += loss_term(x.y, t.y);
        acc += loss_term(x.z, t.z);
        acc += loss_term(x.w, t.w);
    }
    // scalar tail (n not divisible by 4)
    for (int i = (n4 << 2) + tid; i < n; i += stride)
        acc += loss_term(logits[i], targets[i]);

    float s = block_reduce(acc);
    if (threadIdx.x == 0) partial[blockIdx.x] = s;
}

__global__ void hausdorff_final(const float* __restrict__ partial,
                                int nblocks,
                                float* __restrict__ out,
                                double inv_n) {
    // single block; accumulate partials in double for safety
    double acc = 0.0;
    for (int i = threadIdx.x; i < nblocks; i += blockDim.x)
        acc += (double)partial[i];

    // wave64 reduce in double via two 32-bit shuffles is messy; use LDS
    __shared__ double smem[256];
    smem[threadIdx.x] = acc;
    __syncthreads();
    for (int half = blockDim.x >> 1; half > 0; half >>= 1) {
        if (threadIdx.x < half) smem[threadIdx.x] += smem[threadIdx.x + half];
        __syncthreads();
    }
    if (threadIdx.x == 0) out[0] = (float)(smem[0] * inv_n);
}

extern "C" void kernel_launch(void* const* d_in, const int* in_sizes, int n_in,
                              void* d_out, int out_size, void* d_ws, size_t ws_size,
                              hipStream_t stream) {
    const float* logits  = (const float*)d_in[0];
    const float* targets = (const float*)d_in[1];
    float* out = (float*)d_out;
    float* partial = (float*)d_ws;

    const int n = in_sizes[0];            // 8*1024*1024
    const int threads = 256;
    int blocks = 4096;                    // 16 blocks/CU worth of waves; BW-saturating
    const int n4 = n >> 2;
    if (blocks > (n4 + threads - 1) / threads)
        blocks = (n4 + threads - 1) / threads > 0 ? (n4 + threads - 1) / threads : 1;

    hausdorff_partial<<<blocks, threads, 0, stream>>>(logits, targets, partial, n);
    hausdorff_final<<<1, 256, 0, stream>>>(partial, blocks, out, 1.0 / (double)n);
}